// Round 13
// baseline (70.671 us; speedup 1.0000x reference)
//
#include <hip/hip_runtime.h>
#include <cstddef>
#include <cstdint>

#define NN 512
#define CC 64
#define BT 48

typedef __bf16 bf16_t;
typedef bf16_t bf16x8 __attribute__((ext_vector_type(8)));
typedef bf16_t bf16x4 __attribute__((ext_vector_type(4)));
typedef float f32x4 __attribute__((ext_vector_type(4)));

// ---- workspace float-word offsets ----
#define OFF_MN    0         // 384 block-mins
#define OFF_MX    384       // 384 block-maxs
#define OFF_FLG   800       // 48 int flags (per-bt Weff ready)
#define OFF_WSB   1024      // ws bf16 [512][512]
#define OFF_WS2B  132096    // ws2 bf16 [512][512]
#define OFF_XBT   263168    // x^T bf16 [48][64][512]
#define OFF_XNB   1049600   // x natural bf16 [48][512][64]
#define OFF_XNR   1836032   // x natural residual bf16
#define OFF_CS0   2622464   // colsum partials f32 [48][8][64]
#define OFF_T1T   2647040   // ts1^T bf16 [64][64]
#define OFF_T2T   2649088   // ts2^T bf16 [64][64]
#define OFF_WEB   2651136   // Weff^T bf16 [48][64][64]
#define OFF_WER   2749440   // residual
#define OFF_VDY   2847744   // v f32 [48][64]

__device__ __forceinline__ f32x4 mfma(bf16x8 a, bf16x8 b, f32x4 c) {
  return __builtin_amdgcn_mfma_f32_16x16x32_bf16(a, b, c, 0, 0, 0);
}
__device__ __forceinline__ int swz_chunk(int r, int c8) {
  return r * 64 + ((c8 ^ (r & 7)) << 3);
}
__device__ __forceinline__ int swz_e(int r, int c) {
  return r * 64 + ((((c >> 3) ^ (r & 7)) << 3)) + (c & 7);
}
__device__ __forceinline__ bf16x8 frag(const bf16_t* sm, int row, int kc) {
  return *(const bf16x8*)(sm + row * 64 + ((kc ^ (row & 7)) << 3));
}
__device__ __forceinline__ void stage64(bf16_t* sm, const bf16_t* g, int ld, int tid) {
#pragma unroll
  for (int j = 0; j < 2; ++j) {
    int id = tid + 256 * j;
    int r = id >> 3, c8 = id & 7;
    bf16x8 v = *(const bf16x8*)(g + (size_t)r * ld + c8 * 8);
    *(bf16x8*)(sm + swz_chunk(r, c8)) = v;
  }
}
__device__ __forceinline__ void stage64f(bf16_t* sm, const float* g, int ld, int tid) {
#pragma unroll
  for (int j = 0; j < 4; ++j) {
    int idx = tid + 256 * j;
    int r = idx >> 4, cc = (idx & 15) * 4;
    float4 v = *(const float4*)(g + (size_t)r * ld + cc);
    bf16x4 o = {(bf16_t)v.x, (bf16_t)v.y, (bf16_t)v.z, (bf16_t)v.w};
    *(bf16x4*)(sm + swz_e(r, cc)) = o;
  }
}
struct bfpair { bf16_t b, r; };
__device__ __forceinline__ bfpair splitbf(float f) {
  bfpair p;
  p.b = (bf16_t)f;
  p.r = (bf16_t)(f - (float)p.b);
  return p;
}

// ======================= k_pre =======================
// b<384: x-prep (XNb/XNr/XBT, colsum); 384..767: minmax strips;
// 768..831: ws2 tiles; 832..839: ws->bf16; 840: ts1^T/ts2^T + flag reset
__global__ __launch_bounds__(256) void k_pre(
    const float* __restrict__ x, const float* __restrict__ wsL,
    const float* __restrict__ ts, const float* __restrict__ wp,
    float* __restrict__ wsf)
{
  __shared__ __align__(16) char pool[32768];
  __shared__ float red[16];
  const int tid = threadIdx.x;
  const int b = blockIdx.x;
  const int w = tid >> 6, l = tid & 63, lh = l >> 4, lr = l & 15, m0 = w * 16;

  if (b < 384) {  // ---- x-prep, bt-grouped ----
    const int bt = (b & 7) + 8 * (b >> 6);
    const int it = (b >> 3) & 7;
    const int i0 = it * 64;
    float (*XsF)[66] = (float(*)[66])pool;
    bf16_t* XBT = (bf16_t*)(wsf + OFF_XBT);
    bf16_t* XNb = (bf16_t*)(wsf + OFF_XNB);
    bf16_t* XNr = (bf16_t*)(wsf + OFF_XNR);
    float* CS0 = wsf + OFF_CS0;
    const float* xg = x + ((size_t)bt * NN + i0) * CC;
    for (int j = 0; j < 4; ++j) {
      int idx = tid + 256 * j;
      int r = idx >> 4, c0v = (idx & 15) * 4;
      float4 v = *(const float4*)(xg + (size_t)r * CC + c0v);
      bfpair p0 = splitbf(v.x), p1 = splitbf(v.y), p2 = splitbf(v.z), p3 = splitbf(v.w);
      bf16x4 vb = {p0.b, p1.b, p2.b, p3.b};
      bf16x4 vr = {p0.r, p1.r, p2.r, p3.r};
      size_t gb = ((size_t)bt * 512 + i0 + r) * 64 + c0v;
      *(bf16x4*)(XNb + gb) = vb;
      *(bf16x4*)(XNr + gb) = vr;
      XsF[c0v + 0][r] = v.x; XsF[c0v + 1][r] = v.y;
      XsF[c0v + 2][r] = v.z; XsF[c0v + 3][r] = v.w;
    }
    __syncthreads();
    {  // x^T bf16 global
      int c = tid >> 2, k0 = (tid & 3) * 16;
      bf16x8 o1, o2;
#pragma unroll
      for (int q = 0; q < 8; ++q) {
        o1[q] = (bf16_t)XsF[c][k0 + q];
        o2[q] = (bf16_t)XsF[c][k0 + 8 + q];
      }
      size_t base = ((size_t)bt * 64 + c) * 512 + i0 + k0;
      *(bf16x8*)(XBT + base) = o1; *(bf16x8*)(XBT + base + 8) = o2;
    }
    if (tid < 64) {
      float s = 0.f;
      for (int r = 0; r < 64; ++r) s += XsF[tid][r];
      CS0[((size_t)bt * 8 + it) * 64 + tid] = s;
    }
    return;
  }
  if (b < 768) {  // ---- minmax strip (x fp32 direct), bt-grouped ----
    const int g = b - 384;
    const int bt = (g & 7) + 8 * (g >> 6);
    const int bx = (g >> 3) & 7;
    bf16_t* WpT  = (bf16_t*)pool;
    bf16_t* Xa   = (bf16_t*)(pool + 8192);
    bf16_t* Hs   = (bf16_t*)(pool + 16384);
    bf16_t* Xcol = (bf16_t*)(pool + 24576);
    for (int j = 0; j < 4; ++j) {
      int idx = tid + 256 * j;
      int r = idx >> 4, cc = (idx & 15) * 4;   // r = cin, cc = cout
      float4 v = *(const float4*)(wp + r * 64 + cc);
      WpT[swz_e(cc + 0, r)] = (bf16_t)v.x;
      WpT[swz_e(cc + 1, r)] = (bf16_t)v.y;
      WpT[swz_e(cc + 2, r)] = (bf16_t)v.z;
      WpT[swz_e(cc + 3, r)] = (bf16_t)v.w;
    }
    stage64f(Xa, x + ((size_t)bt * NN + bx * 64) * CC, 64, tid);
    __syncthreads();
    f32x4 hacc[4] = {};
#pragma unroll
    for (int q = 0; q < 2; ++q) {
      bf16x8 a = frag(Xa, m0 + lr, q * 4 + lh);
#pragma unroll
      for (int t = 0; t < 4; ++t)
        hacc[t] = mfma(a, frag(WpT, t * 16 + lr, q * 4 + lh), hacc[t]);
    }
#pragma unroll
    for (int t = 0; t < 4; ++t)
#pragma unroll
      for (int r_ = 0; r_ < 4; ++r_)
        Hs[swz_e(m0 + 4 * lh + r_, t * 16 + lr)] = (bf16_t)hacc[t][r_];
    float mn = 3.4e38f, mx = -3.4e38f;
    for (int byj = 0; byj < 8; ++byj) {
      __syncthreads();
      stage64f(Xcol, x + ((size_t)bt * NN + byj * 64) * CC, 64, tid);
      __syncthreads();
      f32x4 acc[4] = {};
#pragma unroll
      for (int q = 0; q < 2; ++q) {
        bf16x8 a = frag(Hs, m0 + lr, q * 4 + lh);
#pragma unroll
        for (int t = 0; t < 4; ++t)
          acc[t] = mfma(a, frag(Xcol, t * 16 + lr, q * 4 + lh), acc[t]);
      }
#pragma unroll
      for (int t = 0; t < 4; ++t)
#pragma unroll
        for (int r_ = 0; r_ < 4; ++r_) {
          mn = fminf(mn, acc[t][r_]); mx = fmaxf(mx, acc[t][r_]);
        }
    }
    for (int off = 32; off; off >>= 1) {
      mn = fminf(mn, __shfl_xor(mn, off));
      mx = fmaxf(mx, __shfl_xor(mx, off));
    }
    if (l == 0) { red[w] = mn; red[8 + w] = mx; }
    __syncthreads();
    if (tid == 0) {
      mn = fminf(fminf(red[0], red[1]), fminf(red[2], red[3]));
      mx = fmaxf(fmaxf(red[8], red[9]), fmaxf(red[10], red[11]));
      wsf[OFF_MN + g] = mn; wsf[OFF_MX + g] = mx;
    }
    return;
  }
  if (b < 832) {  // ---- ws2 tile ----
    const int idx2 = b - 768;
    bf16_t* Asb = (bf16_t*)pool;
    bf16_t* Bsb = (bf16_t*)(pool + 8192);
    bf16_t* Ys  = (bf16_t*)(pool + 16384);
    bf16_t* WS2B = (bf16_t*)(wsf + OFF_WS2B);
    const int r0 = (idx2 >> 3) * 64, c0 = (idx2 & 7) * 64;
    f32x4 acc[4] = {};
    for (int jj = 0; jj < 8; ++jj) {
      if (jj) __syncthreads();
      for (int j = 0; j < 4; ++j) {
        int idx = tid + 256 * j;
        int r = idx >> 4, cc = (idx & 15) * 4;
        float4 v = *(const float4*)(wsL + (size_t)(r0 + r) * 512 + jj * 64 + cc);
        bf16x4 vb = {(bf16_t)v.x, (bf16_t)v.y, (bf16_t)v.z, (bf16_t)v.w};
        *(bf16x4*)(Asb + swz_e(r, cc)) = vb;
        float4 u = *(const float4*)(wsL + (size_t)(jj * 64 + r) * 512 + c0 + cc);
        Bsb[swz_e(cc + 0, r)] = (bf16_t)u.x;
        Bsb[swz_e(cc + 1, r)] = (bf16_t)u.y;
        Bsb[swz_e(cc + 2, r)] = (bf16_t)u.z;
        Bsb[swz_e(cc + 3, r)] = (bf16_t)u.w;
      }
      __syncthreads();
#pragma unroll
      for (int q = 0; q < 2; ++q) {
        bf16x8 a = frag(Asb, m0 + lr, q * 4 + lh);
#pragma unroll
        for (int t = 0; t < 4; ++t)
          acc[t] = mfma(a, frag(Bsb, t * 16 + lr, q * 4 + lh), acc[t]);
      }
    }
#pragma unroll
    for (int t = 0; t < 4; ++t)
#pragma unroll
      for (int r_ = 0; r_ < 4; ++r_) {
        int row = m0 + 4 * lh + r_, col = t * 16 + lr;
        float v = 2.0f * acc[t][r_] - ((r0 + row) == (c0 + col) ? 1.0f : 0.0f);
        Ys[swz_e(row, col)] = (bf16_t)v;
      }
    __syncthreads();
#pragma unroll
    for (int j = 0; j < 2; ++j) {
      int id = tid + 256 * j;
      int r = id >> 3, c8 = id & 7;
      *(bf16x8*)(WS2B + (size_t)(r0 + r) * 512 + c0 + c8 * 8) =
          *(const bf16x8*)(Ys + swz_chunk(r, c8));
    }
    return;
  }
  if (b < 840) {  // ---- ws -> bf16 ----
    const int bx = b - 832;
    const float* wrow = wsL + (size_t)bx * 64 * 512;
    bf16_t* wob = (bf16_t*)(wsf + OFF_WSB) + (size_t)bx * 64 * 512;
    for (int j = 0; j < 32; ++j) {
      int idx = tid + 256 * j;
      float4 v = *(const float4*)(wrow + (size_t)idx * 4);
      bf16x4 o = {(bf16_t)v.x, (bf16_t)v.y, (bf16_t)v.z, (bf16_t)v.w};
      *(bf16x4*)(wob + (size_t)idx * 4) = o;
    }
    return;
  }
  {  // ---- weights transposed + flag reset ----
    bf16_t* T1 = (bf16_t*)(wsf + OFF_T1T);
    bf16_t* T2 = (bf16_t*)(wsf + OFF_T2T);
    const float* t1g = ts + 4096;
    const float* t2g = ts + 8192;
    for (int j = 0; j < 16; ++j) {
      int idx = tid + 256 * j;
      int cin = idx >> 6, co = idx & 63;
      T1[co * 64 + cin] = (bf16_t)t1g[cin * 64 + co];
      T2[co * 64 + cin] = (bf16_t)t2g[cin * 64 + co];
    }
    if (tid < 48) ((int*)(wsf + OFF_FLG))[tid] = 0;
  }
}

// ======================= k_fuse =======================
// bid<48: dyn per bt -> Weff/v (global) + release flag[bt]
// bid>=48: Z1/Z2 K=512 dual GEMM (Z in regs) -> spin flag[bt] -> epilogue
__global__ __launch_bounds__(256) void k_fuse(
    const float* __restrict__ ts, const float* __restrict__ wp,
    const float* __restrict__ td, float* __restrict__ wsf,
    float* __restrict__ out)
{
  __shared__ __align__(16) char pool[66688];
  const int tid = threadIdx.x;
  const int bid = blockIdx.x;
  const int w = tid >> 6, l = tid & 63, lh = l >> 4, lr = l & 15, m0 = w * 16;
  int* flags = (int*)(wsf + OFF_FLG);

  if (bid >= 48) {  // ---------- Z-GEMM + epilogue block ----------
    const int g = bid - 48;
    const int bt = (g & 7) + 8 * (g >> 6);
    const int n0 = ((g >> 3) & 7) * 64;
    bf16_t* As  = (bf16_t*)pool;             // -> Z1s
    bf16_t* B1  = (bf16_t*)(pool + 8192);    // -> Z2s
    bf16_t* B2  = (bf16_t*)(pool + 16384);   // -> WEs
    bf16_t* WRs = (bf16_t*)(pool + 24576);
    bf16_t* Xb  = (bf16_t*)(pool + 32768);
    bf16_t* Xr  = (bf16_t*)(pool + 40960);
    bf16_t* T1s = (bf16_t*)(pool + 49152);
    bf16_t* T2s = (bf16_t*)(pool + 57344);
    // prefetch epilogue operands (regions untouched by GEMM)
    stage64(Xb,  (const bf16_t*)(wsf + OFF_XNB) + ((size_t)bt * 512 + n0) * 64, 64, tid);
    stage64(Xr,  (const bf16_t*)(wsf + OFF_XNR) + ((size_t)bt * 512 + n0) * 64, 64, tid);
    stage64(T1s, (const bf16_t*)(wsf + OFF_T1T), 64, tid);
    stage64(T2s, (const bf16_t*)(wsf + OFF_T2T), 64, tid);
    const bf16_t* XBT = (const bf16_t*)(wsf + OFF_XBT);
    const bf16_t* WSB = (const bf16_t*)(wsf + OFF_WSB);
    const bf16_t* WS2B = (const bf16_t*)(wsf + OFF_WS2B);
    f32x4 acc1[4] = {}, acc2[4] = {};
    for (int kk = 0; kk < 8; ++kk) {
      if (kk) __syncthreads();
      stage64(As, XBT + (size_t)bt * 32768 + kk * 64, 512, tid);
      stage64(B1, WSB + (size_t)n0 * 512 + kk * 64, 512, tid);
      stage64(B2, WS2B + (size_t)n0 * 512 + kk * 64, 512, tid);
      __syncthreads();
#pragma unroll
      for (int q = 0; q < 2; ++q) {
        bf16x8 a = frag(As, m0 + lr, q * 4 + lh);
#pragma unroll
        for (int t = 0; t < 4; ++t) {
          acc1[t] = mfma(a, frag(B1, t * 16 + lr, q * 4 + lh), acc1[t]);
          acc2[t] = mfma(a, frag(B2, t * 16 + lr, q * 4 + lh), acc2[t]);
        }
      }
    }
    __syncthreads();  // all GEMM LDS reads done
    // scatter Z (transposed -> natural [n][c]) into As/B1 regions
#pragma unroll
    for (int t = 0; t < 4; ++t)
#pragma unroll
      for (int r_ = 0; r_ < 4; ++r_) {
        int cy = m0 + 4 * lh + r_, nl = t * 16 + lr;
        As[swz_e(nl, cy)] = (bf16_t)acc1[t][r_];
        B1[swz_e(nl, cy)] = (bf16_t)acc2[t][r_];
      }
    // wait for this bt's Weff (agent-scope acquire; co-residency guaranteed:
    // 66688 B LDS -> exactly 2 blocks/CU -> 512 slots >= 432 blocks)
    if (tid == 0) {
      while (__hip_atomic_load(flags + bt, __ATOMIC_ACQUIRE,
                               __HIP_MEMORY_SCOPE_AGENT) == 0)
        __builtin_amdgcn_s_sleep(8);
    }
    __syncthreads();
    stage64(B2,  (const bf16_t*)(wsf + OFF_WEB) + (size_t)bt * 4096, 64, tid);
    stage64(WRs, (const bf16_t*)(wsf + OFF_WER) + (size_t)bt * 4096, 64, tid);
    __syncthreads();
    const float* VDY = wsf + OFF_VDY;
    f32x4 accO[4];
#pragma unroll
    for (int t = 0; t < 4; ++t) {
      float vv = VDY[bt * 64 + t * 16 + lr];
      accO[t] = {vv, vv, vv, vv};
    }
#pragma unroll
    for (int q = 0; q < 2; ++q) {
      bf16x8 aXb = frag(Xb, m0 + lr, q * 4 + lh);
      bf16x8 aXr = frag(Xr, m0 + lr, q * 4 + lh);
      bf16x8 aZ1 = frag(As, m0 + lr, q * 4 + lh);
      bf16x8 aZ2 = frag(B1, m0 + lr, q * 4 + lh);
#pragma unroll
      for (int t = 0; t < 4; ++t) {
        bf16x8 bWb = frag(B2, t * 16 + lr, q * 4 + lh);
        bf16x8 bWr = frag(WRs, t * 16 + lr, q * 4 + lh);
        accO[t] = mfma(aXb, bWb, accO[t]);
        accO[t] = mfma(aXb, bWr, accO[t]);
        accO[t] = mfma(aXr, bWb, accO[t]);
        accO[t] = mfma(aZ1, frag(T1s, t * 16 + lr, q * 4 + lh), accO[t]);
        accO[t] = mfma(aZ2, frag(T2s, t * 16 + lr, q * 4 + lh), accO[t]);
      }
    }
#pragma unroll
    for (int t = 0; t < 4; ++t)
#pragma unroll
      for (int r_ = 0; r_ < 4; ++r_)
        out[((size_t)bt * 512 + n0 + m0 + 4 * lh + r_) * 64 + t * 16 + lr] = accO[t][r_];
    return;
  }
  // ---------- dyn block ----------
  const int bt = bid;
  bf16_t* XB  = (bf16_t*)pool;   // phase A only
  bf16_t* Ab0 = (bf16_t*)pool;
  bf16_t* AT0 = (bf16_t*)(pool + 8192);
  bf16_t* Ab1 = (bf16_t*)(pool + 16384);
  bf16_t* AT1 = (bf16_t*)(pool + 24576);
  bf16_t* Gb  = (bf16_t*)(pool + 32768);
  bf16_t* WpT = (bf16_t*)(pool + 40960);
  bf16_t* tdA = (bf16_t*)(pool + 49152);
  bf16_t* tdB = (bf16_t*)(pool + 57344);
  float* vec = (float*)(pool + 65536);
  float* uF = vec;        float* hF = vec + 64;
  float* b0 = vec + 128;  float* b1 = vec + 192;
  float* redv = vec + 256;  // 16
  const bf16_t* XBTg = (const bf16_t*)(wsf + OFF_XBT);
  const float* CS0 = wsf + OFF_CS0;
  for (int kk = 0; kk < 8; ++kk)
    stage64(XB + kk * 4096, XBTg + (size_t)bt * 32768 + kk * 64, 512, tid);
  {
    float mn = 3.4e38f, mx = -3.4e38f;
    for (int i = tid; i < 384; i += 256) {
      mn = fminf(mn, wsf[OFF_MN + i]);
      mx = fmaxf(mx, wsf[OFF_MX + i]);
    }
    for (int off = 32; off; off >>= 1) {
      mn = fminf(mn, __shfl_xor(mn, off));
      mx = fmaxf(mx, __shfl_xor(mx, off));
    }
    if (l == 0) { redv[w] = mn; redv[8 + w] = mx; }
  }
  if (tid < 64) {
    float s = 0.f;
#pragma unroll
    for (int p = 0; p < 8; ++p) s += CS0[((size_t)bt * 8 + p) * 64 + tid];
    uF[tid] = s; b0[tid] = s;
  }
  __syncthreads();
  f32x4 pacc[4] = {};
  for (int kk = 0; kk < 8; ++kk) {
    const bf16_t* xt = XB + kk * 4096;
#pragma unroll
    for (int q = 0; q < 2; ++q) {
      bf16x8 a = frag(xt, m0 + lr, q * 4 + lh);
#pragma unroll
      for (int t = 0; t < 4; ++t)
        pacc[t] = mfma(a, frag(xt, t * 16 + lr, q * 4 + lh), pacc[t]);
    }
  }
  const float mnA = fminf(fminf(redv[0], redv[1]), fminf(redv[2], redv[3]));
  const float mxA = fmaxf(fmaxf(redv[8], redv[9]), fmaxf(redv[10], redv[11]));
  const float s_sc = 1.0f / (mxA + mnA) / 262144.0f;
  const float c_sc = mnA * s_sc;
  __syncthreads();  // XB reads done before overwrite
#pragma unroll
  for (int t = 0; t < 4; ++t)
#pragma unroll
    for (int r_ = 0; r_ < 4; ++r_) {
      int m = m0 + 4 * lh + r_, jc = t * 16 + lr;
      bf16_t bv = (bf16_t)pacc[t][r_];
      Ab0[swz_e(m, jc)] = bv; AT0[swz_e(jc, m)] = bv;
    }
  for (int j = 0; j < 4; ++j) {
    int idx = tid + 256 * j;
    int r = idx >> 4, cc = (idx & 15) * 4;
    float4 v = *(const float4*)(wp + r * 64 + cc);
    WpT[swz_e(cc + 0, r)] = (bf16_t)v.x;
    WpT[swz_e(cc + 1, r)] = (bf16_t)v.y;
    WpT[swz_e(cc + 2, r)] = (bf16_t)v.z;
    WpT[swz_e(cc + 3, r)] = (bf16_t)v.w;
  }
  for (int j = 0; j < 4; ++j) {
    int idx = tid + 256 * j;
    int cin = idx >> 4, co = (idx & 15) * 4;
    float4 v = *(const float4*)(td + 4096 + cin * 64 + co);
    tdA[swz_e(co + 0, cin)] = (bf16_t)v.x;
    tdA[swz_e(co + 1, cin)] = (bf16_t)v.y;
    tdA[swz_e(co + 2, cin)] = (bf16_t)v.z;
    tdA[swz_e(co + 3, cin)] = (bf16_t)v.w;
  }
  __syncthreads();
  {  // h = wp^T u
    int jj = tid >> 2, sub = tid & 3;
    float s = 0.f;
    for (int c = sub * 16; c < sub * 16 + 16; ++c)
      s += (float)WpT[swz_e(jj, c)] * uF[c];
    s += __shfl_xor(s, 1); s += __shfl_xor(s, 2);
    if (sub == 0) hF[jj] = s;
  }
  {  // G = P0 @ wp
    f32x4 gv[4] = {};
#pragma unroll
    for (int q = 0; q < 2; ++q) {
      bf16x8 a = frag(Ab0, m0 + lr, q * 4 + lh);
#pragma unroll
      for (int t = 0; t < 4; ++t)
        gv[t] = mfma(a, frag(WpT, t * 16 + lr, q * 4 + lh), gv[t]);
    }
#pragma unroll
    for (int t = 0; t < 4; ++t)
#pragma unroll
      for (int r_ = 0; r_ < 4; ++r_)
        Gb[swz_e(m0 + 4 * lh + r_, t * 16 + lr)] = (bf16_t)gv[t][r_];
  }
  __syncthreads();
  float mu = 0.f, vacc = 0.f;
  f32x4 Macc[4] = {};
  for (int i = 1; i <= 5; ++i) {
    const float* bcur = (i & 1) ? b0 : b1;
    float* bnx = (i & 1) ? b1 : b0;
    const bf16_t* tdc = (i & 1) ? tdA : tdB;
    const bf16_t* AbC = (i & 1) ? Ab0 : Ab1;
    const bf16_t* ATC = (i & 1) ? AT0 : AT1;
    bf16_t* AbN = (i & 1) ? Ab1 : Ab0;
    bf16_t* ATN = (i & 1) ? AT1 : AT0;
    if (i < 5) {
      bf16_t* tdn = (i & 1) ? tdB : tdA;
      for (int j = 0; j < 4; ++j) {
        int idx = tid + 256 * j;
        int cin = idx >> 4, co = (idx & 15) * 4;
        float4 v = *(const float4*)(td + (i + 1) * 4096 + cin * 64 + co);
        tdn[swz_e(co + 0, cin)] = (bf16_t)v.x;
        tdn[swz_e(co + 1, cin)] = (bf16_t)v.y;
        tdn[swz_e(co + 2, cin)] = (bf16_t)v.z;
        tdn[swz_e(co + 3, cin)] = (bf16_t)v.w;
      }
    }
#pragma unroll
    for (int q = 0; q < 2; ++q) {
      bf16x8 a = frag(AbC, m0 + lr, q * 4 + lh);
#pragma unroll
      for (int t = 0; t < 4; ++t)
        Macc[t] = mfma(a, frag(tdc, t * 16 + lr, q * 4 + lh), Macc[t]);
    }
    f32x4 Aacc[4] = {};
    if (i < 5) {
#pragma unroll
      for (int q = 0; q < 2; ++q) {
        bf16x8 gfr = frag(Gb, m0 + lr, q * 4 + lh);
#pragma unroll
        for (int t = 0; t < 4; ++t)
          Aacc[t] = mfma(gfr, frag(ATC, t * 16 + lr, q * 4 + lh), Aacc[t]);
      }
    }
    {
      int co = tid >> 2, sub = tid & 3;
      float sv = 0.f;
      for (int c = sub * 16; c < sub * 16 + 16; ++c)
        sv += bcur[c] * (float)tdc[swz_e(co, c)];
      sv += __shfl_xor(sv, 1); sv += __shfl_xor(sv, 2);
      if (sub == 0) vacc += sv;
    }
    if (i < 5) {
      int jj = tid >> 2, sub = tid & 3;
      float t1 = 0.f;
      for (int m = sub * 16; m < sub * 16 + 16; ++m)
        t1 += (float)ATC[swz_e(jj, m)] * hF[m];
      t1 += __shfl_xor(t1, 1); t1 += __shfl_xor(t1, 2);
      if (sub == 0)
        bnx[jj] = 2.f * (s_sc * t1 + 512.f * c_sc * bcur[jj] + mu * uF[jj])
                  - (i >= 2 ? uF[jj] : 0.f);
    }
    if (i < 5) {
#pragma unroll
      for (int t = 0; t < 4; ++t)
#pragma unroll
        for (int r_ = 0; r_ < 4; ++r_) {
          int m = m0 + 4 * lh + r_, jc = t * 16 + lr;
          float v = 2.f * (s_sc * Aacc[t][r_] + c_sc * uF[m] * bcur[jc] + mu * pacc[t][r_])
                    - (i >= 2 ? pacc[t][r_] : 0.f);
          bf16_t bv = (bf16_t)v;
          AbN[swz_e(m, jc)] = bv; ATN[swz_e(jc, m)] = bv;
        }
      mu = (i == 1) ? -1.f : 0.f;
    }
    __syncthreads();
  }
  bf16_t* Mst = tdA;  // dead
  bf16_t* WpN = tdB;  // dead
#pragma unroll
  for (int t = 0; t < 4; ++t)
#pragma unroll
    for (int r_ = 0; r_ < 4; ++r_)
      Mst[swz_e(t * 16 + lr, m0 + 4 * lh + r_)] = (bf16_t)Macc[t][r_];  // M^T
  for (int j = 0; j < 4; ++j) {
    int idx = tid + 256 * j;
    int r = idx >> 4, cc = (idx & 15) * 4;
    float4 v = *(const float4*)(wp + r * 64 + cc);
    bf16x4 o = {(bf16_t)v.x, (bf16_t)v.y, (bf16_t)v.z, (bf16_t)v.w};
    *(bf16x4*)(WpN + swz_e(r, cc)) = o;
  }
  __syncthreads();
  f32x4 wm[4] = {};
#pragma unroll
  for (int q = 0; q < 2; ++q) {
    bf16x8 a = frag(WpN, m0 + lr, q * 4 + lh);
#pragma unroll
    for (int t = 0; t < 4; ++t)
      wm[t] = mfma(a, frag(Mst, t * 16 + lr, q * 4 + lh), wm[t]);
  }
  bf16_t* WEb = (bf16_t*)(wsf + OFF_WEB);
  bf16_t* WEr = (bf16_t*)(wsf + OFF_WER);
#pragma unroll
  for (int t = 0; t < 4; ++t)
#pragma unroll
    for (int r_ = 0; r_ < 4; ++r_) {
      int a_ = m0 + 4 * lh + r_, co = t * 16 + lr;
      float weff = ts[a_ * 64 + co] + td[a_ * 64 + co] - td[2 * 4096 + a_ * 64 + co]
                   + s_sc * wm[t][r_];
      bfpair p = splitbf(weff);
      WEb[((size_t)bt * 64 + co) * 64 + a_] = p.b;
      WEr[((size_t)bt * 64 + co) * 64 + a_] = p.r;
    }
  if ((tid & 3) == 0) (wsf + OFF_VDY)[bt * 64 + (tid >> 2)] = c_sc * vacc;
  __syncthreads();  // all threads' Weff/v stores issued & complete (vmcnt drained)
  if (tid == 0) {
    __threadfence();  // agent-scope release: writeback L2 so other XCDs see Weff
    __hip_atomic_store(flags + bt, 1, __ATOMIC_RELEASE, __HIP_MEMORY_SCOPE_AGENT);
  }
}

extern "C" void kernel_launch(void* const* d_in, const int* in_sizes, int n_in,
                              void* d_out, int out_size, void* d_ws, size_t ws_size,
                              hipStream_t stream)
{
  (void)in_sizes; (void)n_in; (void)out_size; (void)ws_size;
  const float* x   = (const float*)d_in[0];
  const float* wsL = (const float*)d_in[1];
  const float* ts  = (const float*)d_in[2];
  const float* wp  = (const float*)d_in[3];
  const float* td  = (const float*)d_in[4];
  float* out = (float*)d_out;
  float* wsf = (float*)d_ws;
  dim3 b(256);

  k_pre <<<841, b, 0, stream>>>(x, wsL, ts, wp, wsf);
  k_fuse<<<432, b, 0, stream>>>(ts, wp, td, wsf, out);
}

// Round 14
// 43.466 us; speedup vs baseline: 1.6259x; 1.6259x over previous
//
#include <hip/hip_runtime.h>
#include <cstddef>
#include <cstdint>

#define NN 512
#define CC 64
#define BT 48

typedef __bf16 bf16_t;
typedef bf16_t bf16x8 __attribute__((ext_vector_type(8)));
typedef bf16_t bf16x4 __attribute__((ext_vector_type(4)));
typedef float f32x4 __attribute__((ext_vector_type(4)));

// ---- workspace float-word offsets ----
#define OFF_MN    0         // 384 block-mins
#define OFF_MX    384       // 384 block-maxs
#define OFF_WSB   1024      // ws bf16 [512][512]
#define OFF_WS2B  132096    // ws2 bf16 [512][512]
#define OFF_XBT   263168    // x^T bf16 [48][64][512]
#define OFF_XNB   1049600   // x natural bf16 [48][512][64]
#define OFF_XNR   1836032   // x natural residual bf16
#define OFF_CS0   2622464   // colsum partials f32 [48][8][64]
#define OFF_T1T   2647040   // ts1^T bf16 [64][64]
#define OFF_T2T   2649088   // ts2^T bf16 [64][64]
#define OFF_Z1N   2651136   // Z1 natural bf16 [48][512][64]
#define OFF_Z2N   3437568   // Z2 natural bf16
#define OFF_WEB   4224000   // Weff^T bf16 [48][64][64]
#define OFF_WER   4322304   // residual
#define OFF_VDY   4420608   // v f32 [48][64]

__device__ __forceinline__ f32x4 mfma(bf16x8 a, bf16x8 b, f32x4 c) {
  return __builtin_amdgcn_mfma_f32_16x16x32_bf16(a, b, c, 0, 0, 0);
}
__device__ __forceinline__ int swz_chunk(int r, int c8) {
  return r * 64 + ((c8 ^ (r & 7)) << 3);
}
__device__ __forceinline__ int swz_e(int r, int c) {
  return r * 64 + ((((c >> 3) ^ (r & 7)) << 3)) + (c & 7);
}
__device__ __forceinline__ bf16x8 frag(const bf16_t* sm, int row, int kc) {
  return *(const bf16x8*)(sm + row * 64 + ((kc ^ (row & 7)) << 3));
}
__device__ __forceinline__ void stage64(bf16_t* sm, const bf16_t* g, int ld, int tid) {
#pragma unroll
  for (int j = 0; j < 2; ++j) {
    int id = tid + 256 * j;
    int r = id >> 3, c8 = id & 7;
    bf16x8 v = *(const bf16x8*)(g + (size_t)r * ld + c8 * 8);
    *(bf16x8*)(sm + swz_chunk(r, c8)) = v;
  }
}
__device__ __forceinline__ void stage64f(bf16_t* sm, const float* g, int ld, int tid) {
#pragma unroll
  for (int j = 0; j < 4; ++j) {
    int idx = tid + 256 * j;
    int r = idx >> 4, cc = (idx & 15) * 4;
    float4 v = *(const float4*)(g + (size_t)r * ld + cc);
    bf16x4 o = {(bf16_t)v.x, (bf16_t)v.y, (bf16_t)v.z, (bf16_t)v.w};
    *(bf16x4*)(sm + swz_e(r, cc)) = o;
  }
}
struct bfpair { bf16_t b, r; };
__device__ __forceinline__ bfpair splitbf(float f) {
  bfpair p;
  p.b = (bf16_t)f;
  p.r = (bf16_t)(f - (float)p.b);
  return p;
}
// dot of one swizzled LDS row-slice (16 cols owned by `sub`) with f32 vec
__device__ __forceinline__ float dot16(const bf16_t* sm, int row, int sub,
                                       const float* vecF) {
  bf16x8 a0 = frag(sm, row, sub * 2);
  bf16x8 a1 = frag(sm, row, sub * 2 + 1);
  float s = 0.f;
#pragma unroll
  for (int q = 0; q < 8; ++q) {
    s += (float)a0[q] * vecF[sub * 16 + q];
    s += (float)a1[q] * vecF[sub * 16 + 8 + q];
  }
  return s;
}

// ======================= k_pre =======================
// b<384: x-prep (XNb/XNr/XBT, colsum); 384..767: minmax strips;
// 768..831: ws2 tiles; 832..839: ws->bf16; 840: ts1^T/ts2^T
__global__ __launch_bounds__(256) void k_pre(
    const float* __restrict__ x, const float* __restrict__ wsL,
    const float* __restrict__ ts, const float* __restrict__ wp,
    float* __restrict__ wsf)
{
  __shared__ __align__(16) char pool[32768];
  __shared__ float red[16];
  const int tid = threadIdx.x;
  const int b = blockIdx.x;
  const int w = tid >> 6, l = tid & 63, lh = l >> 4, lr = l & 15, m0 = w * 16;

  if (b < 384) {  // ---- x-prep, bt-grouped ----
    const int bt = (b & 7) + 8 * (b >> 6);
    const int it = (b >> 3) & 7;
    const int i0 = it * 64;
    float (*XsF)[66] = (float(*)[66])pool;
    bf16_t* XBT = (bf16_t*)(wsf + OFF_XBT);
    bf16_t* XNb = (bf16_t*)(wsf + OFF_XNB);
    bf16_t* XNr = (bf16_t*)(wsf + OFF_XNR);
    float* CS0 = wsf + OFF_CS0;
    const float* xg = x + ((size_t)bt * NN + i0) * CC;
    for (int j = 0; j < 4; ++j) {
      int idx = tid + 256 * j;
      int r = idx >> 4, c0v = (idx & 15) * 4;
      float4 v = *(const float4*)(xg + (size_t)r * CC + c0v);
      bfpair p0 = splitbf(v.x), p1 = splitbf(v.y), p2 = splitbf(v.z), p3 = splitbf(v.w);
      bf16x4 vb = {p0.b, p1.b, p2.b, p3.b};
      bf16x4 vr = {p0.r, p1.r, p2.r, p3.r};
      size_t gb = ((size_t)bt * 512 + i0 + r) * 64 + c0v;
      *(bf16x4*)(XNb + gb) = vb;
      *(bf16x4*)(XNr + gb) = vr;
      XsF[c0v + 0][r] = v.x; XsF[c0v + 1][r] = v.y;
      XsF[c0v + 2][r] = v.z; XsF[c0v + 3][r] = v.w;
    }
    __syncthreads();
    {  // x^T bf16 global
      int c = tid >> 2, k0 = (tid & 3) * 16;
      bf16x8 o1, o2;
#pragma unroll
      for (int q = 0; q < 8; ++q) {
        o1[q] = (bf16_t)XsF[c][k0 + q];
        o2[q] = (bf16_t)XsF[c][k0 + 8 + q];
      }
      size_t base = ((size_t)bt * 64 + c) * 512 + i0 + k0;
      *(bf16x8*)(XBT + base) = o1; *(bf16x8*)(XBT + base + 8) = o2;
    }
    if (tid < 64) {
      float s = 0.f;
      for (int r = 0; r < 64; ++r) s += XsF[tid][r];
      CS0[((size_t)bt * 8 + it) * 64 + tid] = s;
    }
    return;
  }
  if (b < 768) {  // ---- minmax strip (x fp32 direct), bt-grouped ----
    const int g = b - 384;
    const int bt = (g & 7) + 8 * (g >> 6);
    const int bx = (g >> 3) & 7;
    bf16_t* WpT  = (bf16_t*)pool;
    bf16_t* Xa   = (bf16_t*)(pool + 8192);
    bf16_t* Hs   = (bf16_t*)(pool + 16384);
    bf16_t* Xcol = (bf16_t*)(pool + 24576);
    for (int j = 0; j < 4; ++j) {
      int idx = tid + 256 * j;
      int r = idx >> 4, cc = (idx & 15) * 4;   // r = cin, cc = cout
      float4 v = *(const float4*)(wp + r * 64 + cc);
      WpT[swz_e(cc + 0, r)] = (bf16_t)v.x;
      WpT[swz_e(cc + 1, r)] = (bf16_t)v.y;
      WpT[swz_e(cc + 2, r)] = (bf16_t)v.z;
      WpT[swz_e(cc + 3, r)] = (bf16_t)v.w;
    }
    stage64f(Xa, x + ((size_t)bt * NN + bx * 64) * CC, 64, tid);
    __syncthreads();
    f32x4 hacc[4] = {};
#pragma unroll
    for (int q = 0; q < 2; ++q) {
      bf16x8 a = frag(Xa, m0 + lr, q * 4 + lh);
#pragma unroll
      for (int t = 0; t < 4; ++t)
        hacc[t] = mfma(a, frag(WpT, t * 16 + lr, q * 4 + lh), hacc[t]);
    }
#pragma unroll
    for (int t = 0; t < 4; ++t)
#pragma unroll
      for (int r_ = 0; r_ < 4; ++r_)
        Hs[swz_e(m0 + 4 * lh + r_, t * 16 + lr)] = (bf16_t)hacc[t][r_];
    float mn = 3.4e38f, mx = -3.4e38f;
    for (int byj = 0; byj < 8; ++byj) {
      __syncthreads();
      stage64f(Xcol, x + ((size_t)bt * NN + byj * 64) * CC, 64, tid);
      __syncthreads();
      f32x4 acc[4] = {};
#pragma unroll
      for (int q = 0; q < 2; ++q) {
        bf16x8 a = frag(Hs, m0 + lr, q * 4 + lh);
#pragma unroll
        for (int t = 0; t < 4; ++t)
          acc[t] = mfma(a, frag(Xcol, t * 16 + lr, q * 4 + lh), acc[t]);
      }
#pragma unroll
      for (int t = 0; t < 4; ++t)
#pragma unroll
        for (int r_ = 0; r_ < 4; ++r_) {
          mn = fminf(mn, acc[t][r_]); mx = fmaxf(mx, acc[t][r_]);
        }
    }
    for (int off = 32; off; off >>= 1) {
      mn = fminf(mn, __shfl_xor(mn, off));
      mx = fmaxf(mx, __shfl_xor(mx, off));
    }
    if (l == 0) { red[w] = mn; red[8 + w] = mx; }
    __syncthreads();
    if (tid == 0) {
      mn = fminf(fminf(red[0], red[1]), fminf(red[2], red[3]));
      mx = fmaxf(fmaxf(red[8], red[9]), fmaxf(red[10], red[11]));
      wsf[OFF_MN + g] = mn; wsf[OFF_MX + g] = mx;
    }
    return;
  }
  if (b < 832) {  // ---- ws2 tile ----
    const int idx2 = b - 768;
    bf16_t* Asb = (bf16_t*)pool;
    bf16_t* Bsb = (bf16_t*)(pool + 8192);
    bf16_t* Ys  = (bf16_t*)(pool + 16384);
    bf16_t* WS2B = (bf16_t*)(wsf + OFF_WS2B);
    const int r0 = (idx2 >> 3) * 64, c0 = (idx2 & 7) * 64;
    f32x4 acc[4] = {};
    for (int jj = 0; jj < 8; ++jj) {
      if (jj) __syncthreads();
      for (int j = 0; j < 4; ++j) {
        int idx = tid + 256 * j;
        int r = idx >> 4, cc = (idx & 15) * 4;
        float4 v = *(const float4*)(wsL + (size_t)(r0 + r) * 512 + jj * 64 + cc);
        bf16x4 vb = {(bf16_t)v.x, (bf16_t)v.y, (bf16_t)v.z, (bf16_t)v.w};
        *(bf16x4*)(Asb + swz_e(r, cc)) = vb;
        float4 u = *(const float4*)(wsL + (size_t)(jj * 64 + r) * 512 + c0 + cc);
        Bsb[swz_e(cc + 0, r)] = (bf16_t)u.x;
        Bsb[swz_e(cc + 1, r)] = (bf16_t)u.y;
        Bsb[swz_e(cc + 2, r)] = (bf16_t)u.z;
        Bsb[swz_e(cc + 3, r)] = (bf16_t)u.w;
      }
      __syncthreads();
#pragma unroll
      for (int q = 0; q < 2; ++q) {
        bf16x8 a = frag(Asb, m0 + lr, q * 4 + lh);
#pragma unroll
        for (int t = 0; t < 4; ++t)
          acc[t] = mfma(a, frag(Bsb, t * 16 + lr, q * 4 + lh), acc[t]);
      }
    }
#pragma unroll
    for (int t = 0; t < 4; ++t)
#pragma unroll
      for (int r_ = 0; r_ < 4; ++r_) {
        int row = m0 + 4 * lh + r_, col = t * 16 + lr;
        float v = 2.0f * acc[t][r_] - ((r0 + row) == (c0 + col) ? 1.0f : 0.0f);
        Ys[swz_e(row, col)] = (bf16_t)v;
      }
    __syncthreads();
#pragma unroll
    for (int j = 0; j < 2; ++j) {
      int id = tid + 256 * j;
      int r = id >> 3, c8 = id & 7;
      *(bf16x8*)(WS2B + (size_t)(r0 + r) * 512 + c0 + c8 * 8) =
          *(const bf16x8*)(Ys + swz_chunk(r, c8));
    }
    return;
  }
  if (b < 840) {  // ---- ws -> bf16 ----
    const int bx = b - 832;
    const float* wrow = wsL + (size_t)bx * 64 * 512;
    bf16_t* wob = (bf16_t*)(wsf + OFF_WSB) + (size_t)bx * 64 * 512;
    for (int j = 0; j < 32; ++j) {
      int idx = tid + 256 * j;
      float4 v = *(const float4*)(wrow + (size_t)idx * 4);
      bf16x4 o = {(bf16_t)v.x, (bf16_t)v.y, (bf16_t)v.z, (bf16_t)v.w};
      *(bf16x4*)(wob + (size_t)idx * 4) = o;
    }
    return;
  }
  {  // ---- weights transposed ----
    bf16_t* T1 = (bf16_t*)(wsf + OFF_T1T);
    bf16_t* T2 = (bf16_t*)(wsf + OFF_T2T);
    const float* t1g = ts + 4096;
    const float* t2g = ts + 8192;
    for (int j = 0; j < 16; ++j) {
      int idx = tid + 256 * j;
      int cin = idx >> 6, co = idx & 63;
      T1[co * 64 + cin] = (bf16_t)t1g[cin * 64 + co];
      T2[co * 64 + cin] = (bf16_t)t2g[cin * 64 + co];
    }
  }
}

// ======================= k_mix =======================
// bid<48: dyn per bt (P0 in regs from XBT panel) -> Weff/v (global)
// bid>=48: Z1/Z2 K=512 dual GEMM -> Z1N/Z2N natural (global); bt-grouped
__global__ __launch_bounds__(256) void k_mix(
    const float* __restrict__ ts, const float* __restrict__ wp,
    const float* __restrict__ td, float* __restrict__ wsf)
{
  __shared__ __align__(16) char pool[66688];
  const int tid = threadIdx.x;
  const int bid = blockIdx.x;
  const int w = tid >> 6, l = tid & 63, lh = l >> 4, lr = l & 15, m0 = w * 16;

  if (bid >= 48) {  // ---------- Z-GEMM block ----------
    const int g = bid - 48;
    const int bt = (g & 7) + 8 * (g >> 6);
    const int n0 = ((g >> 3) & 7) * 64;
    bf16_t* As = (bf16_t*)pool;
    bf16_t* B1 = (bf16_t*)(pool + 8192);
    bf16_t* B2 = (bf16_t*)(pool + 16384);
    const bf16_t* XBT = (const bf16_t*)(wsf + OFF_XBT);
    const bf16_t* WSB = (const bf16_t*)(wsf + OFF_WSB);
    const bf16_t* WS2B = (const bf16_t*)(wsf + OFF_WS2B);
    f32x4 acc1[4] = {}, acc2[4] = {};
    for (int kk = 0; kk < 8; ++kk) {
      if (kk) __syncthreads();
      stage64(As, XBT + (size_t)bt * 32768 + kk * 64, 512, tid);
      stage64(B1, WSB + (size_t)n0 * 512 + kk * 64, 512, tid);
      stage64(B2, WS2B + (size_t)n0 * 512 + kk * 64, 512, tid);
      __syncthreads();
#pragma unroll
      for (int q = 0; q < 2; ++q) {
        bf16x8 a = frag(As, m0 + lr, q * 4 + lh);
#pragma unroll
        for (int t = 0; t < 4; ++t) {
          acc1[t] = mfma(a, frag(B1, t * 16 + lr, q * 4 + lh), acc1[t]);
          acc2[t] = mfma(a, frag(B2, t * 16 + lr, q * 4 + lh), acc2[t]);
        }
      }
    }
    __syncthreads();
#pragma unroll
    for (int t = 0; t < 4; ++t)
#pragma unroll
      for (int r_ = 0; r_ < 4; ++r_) {
        int cy = m0 + 4 * lh + r_, nl = t * 16 + lr;
        As[swz_e(nl, cy)] = (bf16_t)acc1[t][r_];
        B1[swz_e(nl, cy)] = (bf16_t)acc2[t][r_];
      }
    __syncthreads();
    bf16_t* Z1N = (bf16_t*)(wsf + OFF_Z1N);
    bf16_t* Z2N = (bf16_t*)(wsf + OFF_Z2N);
#pragma unroll
    for (int j = 0; j < 2; ++j) {
      int id = tid + 256 * j;
      int r = id >> 3, c8 = id & 7;
      size_t gb = ((size_t)bt * 512 + n0 + r) * 64 + c8 * 8;
      *(bf16x8*)(Z1N + gb) = *(const bf16x8*)(As + swz_chunk(r, c8));
      *(bf16x8*)(Z2N + gb) = *(const bf16x8*)(B1 + swz_chunk(r, c8));
    }
    return;
  }
  // ---------- dyn block ----------
  const int bt = bid;
  bf16_t* XB  = (bf16_t*)pool;   // phase A only (overlaps all buffers below)
  bf16_t* Ab0 = (bf16_t*)pool;
  bf16_t* AT0 = (bf16_t*)(pool + 8192);
  bf16_t* Ab1 = (bf16_t*)(pool + 16384);
  bf16_t* AT1 = (bf16_t*)(pool + 24576);
  bf16_t* Gb  = (bf16_t*)(pool + 32768);
  bf16_t* WpT = (bf16_t*)(pool + 40960);
  bf16_t* tdA = (bf16_t*)(pool + 49152);
  bf16_t* tdB = (bf16_t*)(pool + 57344);
  float* vec = (float*)(pool + 65536);
  float* uF = vec;        float* hF = vec + 64;
  float* b0 = vec + 128;  float* b1 = vec + 192;
  float* redv = vec + 256;  // 16
  const bf16_t* XBTg = (const bf16_t*)(wsf + OFF_XBT);
  const float* CS0 = wsf + OFF_CS0;
  // phase A: stage x^T panel; min/max reduce; u
  for (int kk = 0; kk < 8; ++kk)
    stage64(XB + kk * 4096, XBTg + (size_t)bt * 32768 + kk * 64, 512, tid);
  {
    float mn = 3.4e38f, mx = -3.4e38f;
    for (int i = tid; i < 384; i += 256) {
      mn = fminf(mn, wsf[OFF_MN + i]);
      mx = fmaxf(mx, wsf[OFF_MX + i]);
    }
    for (int off = 32; off; off >>= 1) {
      mn = fminf(mn, __shfl_xor(mn, off));
      mx = fmaxf(mx, __shfl_xor(mx, off));
    }
    if (l == 0) { redv[w] = mn; redv[8 + w] = mx; }
  }
  if (tid < 64) {
    float s = 0.f;
#pragma unroll
    for (int p = 0; p < 8; ++p) s += CS0[((size_t)bt * 8 + p) * 64 + tid];
    uF[tid] = s; b0[tid] = s;
  }
  __syncthreads();
  // P0 = x^T x via MFMA over 8 resident tiles -> regs
  f32x4 pacc[4] = {};
  for (int kk = 0; kk < 8; ++kk) {
    const bf16_t* xt = XB + kk * 4096;
#pragma unroll
    for (int q = 0; q < 2; ++q) {
      bf16x8 a = frag(xt, m0 + lr, q * 4 + lh);
#pragma unroll
      for (int t = 0; t < 4; ++t)
        pacc[t] = mfma(a, frag(xt, t * 16 + lr, q * 4 + lh), pacc[t]);
    }
  }
  const float mnA = fminf(fminf(redv[0], redv[1]), fminf(redv[2], redv[3]));
  const float mxA = fmaxf(fmaxf(redv[8], redv[9]), fmaxf(redv[10], redv[11]));
  const float s_sc = 1.0f / (mxA + mnA) / 262144.0f;
  const float c_sc = mnA * s_sc;
  __syncthreads();  // all XB reads done before overwriting with recurrence bufs
  // setup: A1 from pacc; wp^T; td1
#pragma unroll
  for (int t = 0; t < 4; ++t)
#pragma unroll
    for (int r_ = 0; r_ < 4; ++r_) {
      int m = m0 + 4 * lh + r_, jc = t * 16 + lr;
      bf16_t bv = (bf16_t)pacc[t][r_];
      Ab0[swz_e(m, jc)] = bv; AT0[swz_e(jc, m)] = bv;
    }
  for (int j = 0; j < 4; ++j) {
    int idx = tid + 256 * j;
    int r = idx >> 4, cc = (idx & 15) * 4;
    float4 v = *(const float4*)(wp + r * 64 + cc);
    WpT[swz_e(cc + 0, r)] = (bf16_t)v.x;
    WpT[swz_e(cc + 1, r)] = (bf16_t)v.y;
    WpT[swz_e(cc + 2, r)] = (bf16_t)v.z;
    WpT[swz_e(cc + 3, r)] = (bf16_t)v.w;
  }
  for (int j = 0; j < 4; ++j) {
    int idx = tid + 256 * j;
    int cin = idx >> 4, co = (idx & 15) * 4;
    float4 v = *(const float4*)(td + 4096 + cin * 64 + co);
    tdA[swz_e(co + 0, cin)] = (bf16_t)v.x;
    tdA[swz_e(co + 1, cin)] = (bf16_t)v.y;
    tdA[swz_e(co + 2, cin)] = (bf16_t)v.z;
    tdA[swz_e(co + 3, cin)] = (bf16_t)v.w;
  }
  __syncthreads();
  {  // h = wp^T u (vectorized ds_read_b128 x2)
    int jj = tid >> 2, sub = tid & 3;
    float s = dot16(WpT, jj, sub, uF);
    s += __shfl_xor(s, 1); s += __shfl_xor(s, 2);
    if (sub == 0) hF[jj] = s;
  }
  {  // G = P0 @ wp
    f32x4 gv[4] = {};
#pragma unroll
    for (int q = 0; q < 2; ++q) {
      bf16x8 a = frag(Ab0, m0 + lr, q * 4 + lh);
#pragma unroll
      for (int t = 0; t < 4; ++t)
        gv[t] = mfma(a, frag(WpT, t * 16 + lr, q * 4 + lh), gv[t]);
    }
#pragma unroll
    for (int t = 0; t < 4; ++t)
#pragma unroll
      for (int r_ = 0; r_ < 4; ++r_)
        Gb[swz_e(m0 + 4 * lh + r_, t * 16 + lr)] = (bf16_t)gv[t][r_];
  }
  __syncthreads();
  float mu = 0.f, vacc = 0.f;
  f32x4 Macc[4] = {};
  for (int i = 1; i <= 5; ++i) {
    const float* bcur = (i & 1) ? b0 : b1;
    float* bnx = (i & 1) ? b1 : b0;
    const bf16_t* tdc = (i & 1) ? tdA : tdB;
    const bf16_t* AbC = (i & 1) ? Ab0 : Ab1;
    const bf16_t* ATC = (i & 1) ? AT0 : AT1;
    bf16_t* AbN = (i & 1) ? Ab1 : Ab0;
    bf16_t* ATN = (i & 1) ? AT1 : AT0;
    if (i < 5) {  // prefetch td_{i+1}
      bf16_t* tdn = (i & 1) ? tdB : tdA;
      for (int j = 0; j < 4; ++j) {
        int idx = tid + 256 * j;
        int cin = idx >> 4, co = (idx & 15) * 4;
        float4 v = *(const float4*)(td + (i + 1) * 4096 + cin * 64 + co);
        tdn[swz_e(co + 0, cin)] = (bf16_t)v.x;
        tdn[swz_e(co + 1, cin)] = (bf16_t)v.y;
        tdn[swz_e(co + 2, cin)] = (bf16_t)v.z;
        tdn[swz_e(co + 3, cin)] = (bf16_t)v.w;
      }
    }
#pragma unroll
    for (int q = 0; q < 2; ++q) {
      bf16x8 a = frag(AbC, m0 + lr, q * 4 + lh);
#pragma unroll
      for (int t = 0; t < 4; ++t)
        Macc[t] = mfma(a, frag(tdc, t * 16 + lr, q * 4 + lh), Macc[t]);
    }
    f32x4 Aacc[4] = {};
    if (i < 5) {
#pragma unroll
      for (int q = 0; q < 2; ++q) {
        bf16x8 gfr = frag(Gb, m0 + lr, q * 4 + lh);
#pragma unroll
        for (int t = 0; t < 4; ++t)
          Aacc[t] = mfma(gfr, frag(ATC, t * 16 + lr, q * 4 + lh), Aacc[t]);
      }
    }
    {  // vacc partial: v_i[co] = sum_c b[c]*td_i[c][co] (vectorized)
      int co = tid >> 2, sub = tid & 3;
      float sv = dot16(tdc, co, sub, bcur);
      sv += __shfl_xor(sv, 1); sv += __shfl_xor(sv, 2);
      if (sub == 0) vacc += sv;
    }
    if (i < 5) {  // t1 = A_i^T h fused with bnext (vectorized)
      int jj = tid >> 2, sub = tid & 3;
      float t1 = dot16(ATC, jj, sub, hF);
      t1 += __shfl_xor(t1, 1); t1 += __shfl_xor(t1, 2);
      if (sub == 0)
        bnx[jj] = 2.f * (s_sc * t1 + 512.f * c_sc * bcur[jj] + mu * uF[jj])
                  - (i >= 2 ? uF[jj] : 0.f);
    }
    if (i < 5) {
#pragma unroll
      for (int t = 0; t < 4; ++t)
#pragma unroll
        for (int r_ = 0; r_ < 4; ++r_) {
          int m = m0 + 4 * lh + r_, jc = t * 16 + lr;
          float v = 2.f * (s_sc * Aacc[t][r_] + c_sc * uF[m] * bcur[jc] + mu * pacc[t][r_])
                    - (i >= 2 ? pacc[t][r_] : 0.f);
          bf16_t bv = (bf16_t)v;
          AbN[swz_e(m, jc)] = bv; ATN[swz_e(jc, m)] = bv;
        }
      mu = (i == 1) ? -1.f : 0.f;
    }
    __syncthreads();
  }
  // WM = wp @ M ; Weff
  bf16_t* Mst = tdA;  // dead
  bf16_t* WpN = tdB;  // dead
#pragma unroll
  for (int t = 0; t < 4; ++t)
#pragma unroll
    for (int r_ = 0; r_ < 4; ++r_)
      Mst[swz_e(t * 16 + lr, m0 + 4 * lh + r_)] = (bf16_t)Macc[t][r_];  // M^T
  for (int j = 0; j < 4; ++j) {  // wp natural
    int idx = tid + 256 * j;
    int r = idx >> 4, cc = (idx & 15) * 4;
    float4 v = *(const float4*)(wp + r * 64 + cc);
    bf16x4 o = {(bf16_t)v.x, (bf16_t)v.y, (bf16_t)v.z, (bf16_t)v.w};
    *(bf16x4*)(WpN + swz_e(r, cc)) = o;
  }
  __syncthreads();
  f32x4 wm[4] = {};
#pragma unroll
  for (int q = 0; q < 2; ++q) {
    bf16x8 a = frag(WpN, m0 + lr, q * 4 + lh);
#pragma unroll
    for (int t = 0; t < 4; ++t)
      wm[t] = mfma(a, frag(Mst, t * 16 + lr, q * 4 + lh), wm[t]);
  }
  bf16_t* WEb = (bf16_t*)(wsf + OFF_WEB);
  bf16_t* WEr = (bf16_t*)(wsf + OFF_WER);
#pragma unroll
  for (int t = 0; t < 4; ++t)
#pragma unroll
    for (int r_ = 0; r_ < 4; ++r_) {
      int a_ = m0 + 4 * lh + r_, co = t * 16 + lr;
      float weff = ts[a_ * 64 + co] + td[a_ * 64 + co] - td[2 * 4096 + a_ * 64 + co]
                   + s_sc * wm[t][r_];
      bfpair p = splitbf(weff);
      WEb[((size_t)bt * 64 + co) * 64 + a_] = p.b;
      WEr[((size_t)bt * 64 + co) * 64 + a_] = p.r;
    }
  if ((tid & 3) == 0) (wsf + OFF_VDY)[bt * 64 + (tid >> 2)] = c_sc * vacc;
}

// ======================= k_epi =======================
// out = x@Weff (split) + Z1@ts1 + Z2@ts2 + 1*v ; bt-grouped
__global__ __launch_bounds__(256) void k_epi(float* __restrict__ wsf,
                                             float* __restrict__ out)
{
  __shared__ __align__(16) bf16_t Xb[4096], Xr[4096], Z1s[4096], Z2s[4096],
                                  WEs[4096], WRs[4096], T1s[4096], T2s[4096];
  const int tid = threadIdx.x;
  const int g = blockIdx.x;
  const int bt = (g & 7) + 8 * (g >> 6);
  const int n0 = ((g >> 3) & 7) * 64;
  const int w = tid >> 6, l = tid & 63, lh = l >> 4, lr = l & 15, m0 = w * 16;
  stage64(Xb,  (const bf16_t*)(wsf + OFF_XNB) + ((size_t)bt * 512 + n0) * 64, 64, tid);
  stage64(Xr,  (const bf16_t*)(wsf + OFF_XNR) + ((size_t)bt * 512 + n0) * 64, 64, tid);
  stage64(Z1s, (const bf16_t*)(wsf + OFF_Z1N) + ((size_t)bt * 512 + n0) * 64, 64, tid);
  stage64(Z2s, (const bf16_t*)(wsf + OFF_Z2N) + ((size_t)bt * 512 + n0) * 64, 64, tid);
  stage64(WEs, (const bf16_t*)(wsf + OFF_WEB) + (size_t)bt * 4096, 64, tid);
  stage64(WRs, (const bf16_t*)(wsf + OFF_WER) + (size_t)bt * 4096, 64, tid);
  stage64(T1s, (const bf16_t*)(wsf + OFF_T1T), 64, tid);
  stage64(T2s, (const bf16_t*)(wsf + OFF_T2T), 64, tid);
  __syncthreads();
  const float* VDY = wsf + OFF_VDY;
  f32x4 accO[4];
#pragma unroll
  for (int t = 0; t < 4; ++t) {
    float vv = VDY[bt * 64 + t * 16 + lr];
    accO[t] = {vv, vv, vv, vv};
  }
#pragma unroll
  for (int q = 0; q < 2; ++q) {
    bf16x8 aXb = frag(Xb, m0 + lr, q * 4 + lh);
    bf16x8 aXr = frag(Xr, m0 + lr, q * 4 + lh);
    bf16x8 aZ1 = frag(Z1s, m0 + lr, q * 4 + lh);
    bf16x8 aZ2 = frag(Z2s, m0 + lr, q * 4 + lh);
#pragma unroll
    for (int t = 0; t < 4; ++t) {
      bf16x8 bWb = frag(WEs, t * 16 + lr, q * 4 + lh);
      bf16x8 bWr = frag(WRs, t * 16 + lr, q * 4 + lh);
      accO[t] = mfma(aXb, bWb, accO[t]);
      accO[t] = mfma(aXb, bWr, accO[t]);
      accO[t] = mfma(aXr, bWb, accO[t]);
      accO[t] = mfma(aZ1, frag(T1s, t * 16 + lr, q * 4 + lh), accO[t]);
      accO[t] = mfma(aZ2, frag(T2s, t * 16 + lr, q * 4 + lh), accO[t]);
    }
  }
#pragma unroll
  for (int t = 0; t < 4; ++t)
#pragma unroll
    for (int r_ = 0; r_ < 4; ++r_)
      out[((size_t)bt * 512 + n0 + m0 + 4 * lh + r_) * 64 + t * 16 + lr] = accO[t][r_];
}

extern "C" void kernel_launch(void* const* d_in, const int* in_sizes, int n_in,
                              void* d_out, int out_size, void* d_ws, size_t ws_size,
                              hipStream_t stream)
{
  (void)in_sizes; (void)n_in; (void)out_size; (void)ws_size;
  const float* x   = (const float*)d_in[0];
  const float* wsL = (const float*)d_in[1];
  const float* ts  = (const float*)d_in[2];
  const float* wp  = (const float*)d_in[3];
  const float* td  = (const float*)d_in[4];
  float* out = (float*)d_out;
  float* wsf = (float*)d_ws;
  dim3 b(256);

  k_pre<<<841, b, 0, stream>>>(x, wsL, ts, wp, wsf);
  k_mix<<<432, b, 0, stream>>>(ts, wp, td, wsf);
  k_epi<<<384, b, 0, stream>>>(wsf, out);
}